// Round 23
// baseline (136.356 us; speedup 1.0000x reference)
//
#include <hip/hip_runtime.h>
#include <stdint.h>

#pragma clang fp contract(off)

#define NN    300000
#define TOPK  6000u
#define KW    94
#define KPAD  6016
#define SORTN 8192
#define OUTK  300
#define ECAP2 2048
#define NREP  8
#define NBLK  256

// ---------------- workspace layout (bytes) ----------------
static constexpr size_t OFF_ROI    = 0;                                   // NN*16
static constexpr size_t OFF_KEY    = OFF_ROI + (size_t)NN * 16;           // NN*4
static constexpr size_t OFF_HIST16 = ((OFF_KEY + (size_t)NN * 4 + 255) & ~(size_t)255); // NREP*65536*4
static constexpr size_t OFF_SCAL   = OFF_HIST16 + (size_t)NREP * 65536 * 4; // 256 B
static constexpr size_t OFF_ECNT   = OFF_SCAL + 256;                      // 94*4 pad 512
static constexpr size_t ZERO_BYTES = (OFF_ECNT + 512) - OFF_HIST16;
static constexpr size_t OFF_HISTS  = OFF_ECNT + 512;                      // 65536*4
static constexpr size_t OFF_BSUM   = OFF_HISTS + 65536 * 4;               // 256*4 pad 1024
static constexpr size_t OFF_SORT   = OFF_BSUM + 1024;                     // SORTN*8
static constexpr size_t OFF_SELBOX = OFF_SORT + (size_t)SORTN * 8;        // KPAD*16
static constexpr size_t OFF_DIAG   = ((OFF_SELBOX + (size_t)KPAD * 16 + 255) & ~(size_t)255); // KPAD*8
static constexpr size_t OFF_ELIST  = OFF_DIAG + (size_t)KPAD * 8;         // KW*ECAP2*4

// scal[]: [0]=P16 bin, [3]=compact counter, [4]=valid total,
//         [8]=hsum done ctr, [9]=mask done ctr

static constexpr uint32_t ZG = (uint32_t)(ZERO_BYTES / 16);
static constexpr uint32_t INIT_BLOCKS = (ZG + 255) / 256;

__device__ __forceinline__ uint32_t score_key(float s) {
  uint32_t u = __float_as_uint(s);
  u = (u >> 31) ? ~u : (u | 0x80000000u);
  return ~u;
}
__device__ __forceinline__ uint32_t hslot(uint32_t b) { return __brev(b) >> 16; }
__device__ __forceinline__ float rlf(float v, int l) {
  return __uint_as_float(__builtin_amdgcn_readlane(__float_as_uint(v), l));
}

// ---------------- 0. workspace init (hist replicas + scal + ecnt) ----------------
__global__ void __launch_bounds__(256) k_init(char* __restrict__ ws) {
  uint32_t idx = blockIdx.x * 256 + threadIdx.x;
  if (idx < ZG)
    ((uint4*)(ws + OFF_HIST16))[idx] = make_uint4(0u, 0u, 0u, 0u);
}

// ---------------- 1. decode + key + replicated 16-bit histogram ----------------
__global__ void k_decode(const float* __restrict__ cls, const float* __restrict__ reg,
                         const float* __restrict__ anchor, float4* __restrict__ roi,
                         uint32_t* __restrict__ key, uint32_t* __restrict__ hist16) {
  int i = blockIdx.x * blockDim.x + threadIdx.x;
  if (i >= NN) return;
  float c0 = cls[2 * i], c1 = cls[2 * i + 1];
  float m  = fmaxf(c0, c1);
  float a0 = c0 - m, a1 = c1 - m;
  float tn = fminf(a0, a1);
  float e  = (float)exp((double)tn);
  float e0 = (a0 == 0.0f) ? 1.0f : e;
  float e1 = (a1 == 0.0f) ? 1.0f : e;
  float s  = e1 / (e0 + e1);

  float4 a = ((const float4*)anchor)[i];
  float acx = (a.x + a.z) * 0.5f;
  float acy = (a.y + a.w) * 0.5f;
  float aw  = a.z - a.x;
  float ah  = a.w - a.y;
  float4 r = ((const float4*)reg)[i];
  float cx = r.x * aw + acx;
  float cy = r.y * ah + acy;
  float w  = (float)exp((double)r.z) * aw;
  float h  = (float)exp((double)r.w) * ah;
  float x1 = cx - w * 0.5f, y1 = cy - h * 0.5f;
  float x2 = cx + w * 0.5f, y2 = cy + h * 0.5f;
  x1 = fminf(fmaxf(x1, 0.0f), 1.0f);
  y1 = fminf(fmaxf(y1, 0.0f), 1.0f);
  x2 = fminf(fmaxf(x2, 0.0f), 1.0f);
  y2 = fminf(fmaxf(y2, 0.0f), 1.0f);
  float ws_ = x2 - x1, hs_ = y2 - y1;
  bool valid = (hs_ >= 0.001f) && (ws_ >= 0.001f);
  float msc = valid ? s : -__builtin_inff();
  uint32_t kk = score_key(msc);

  roi[i] = make_float4(x1, y1, x2, y2);
  key[i] = kk;
  if (valid) atomicAdd(&hist16[((blockIdx.x & (NREP - 1)) << 16) + hslot(kk >> 16)], 1u);
}

// ---------------- 2. hsum (256 blocks) + LAST BLOCK runs hierarchical scan --------
__global__ void __launch_bounds__(256) k_hsumS(const uint32_t* __restrict__ hist16,
                                               uint32_t* __restrict__ hists,
                                               uint32_t* __restrict__ bsum,
                                               int* __restrict__ scal) {
  __shared__ uint32_t red[256];
  __shared__ uint32_t cum[256];
  __shared__ int Bs;
  __shared__ int lastblk;
  int t = threadIdx.x;
  int b = blockIdx.x * 256 + t;
  uint32_t slot = hslot((uint32_t)b);
  uint32_t s = 0;
#pragma unroll
  for (int r = 0; r < NREP; r++) s += hist16[(r << 16) + slot];
  hists[b] = s;
  red[t] = s;
  __syncthreads();
  for (int off = 128; off > 0; off >>= 1) {
    if (t < off) red[t] += red[t + off];
    __syncthreads();
  }
  if (t == 0) bsum[blockIdx.x] = red[0];

  __syncthreads();
  if (t == 0) {
    __threadfence();
    uint32_t old = atomicAdd((uint32_t*)&scal[8], 1u);
    lastblk = (old == (uint32_t)(gridDim.x - 1));
  }
  __syncthreads();
  if (!lastblk) return;
  __threadfence();

  uint32_t v = bsum[t];
  cum[t] = v;
  if (t == 0) Bs = 256;
  __syncthreads();
  for (int off = 1; off < 256; off <<= 1) {
    uint32_t x = (t >= off) ? cum[t - off] : 0;
    __syncthreads();
    cum[t] += x;
    __syncthreads();
  }
  if (t == 255) scal[4] = (int)cum[255];
  if (cum[t] >= TOPK && (t == 0 || cum[t - 1] < TOPK)) Bs = t;
  __syncthreads();
  int B = Bs;
  if (B == 256) { if (t == 0) scal[0] = 65535; return; }
  uint32_t cumbase = (B > 0) ? cum[B - 1] : 0;
  __syncthreads();
  uint32_t h2 = hists[B * 256 + t];
  cum[t] = h2;
  __syncthreads();
  for (int off = 1; off < 256; off <<= 1) {
    uint32_t x = (t >= off) ? cum[t - off] : 0;
    __syncthreads();
    cum[t] += x;
    __syncthreads();
  }
  uint32_t cc = cumbase + cum[t];
  uint32_t cp = cc - h2;
  if (cc >= TOPK && cp < TOPK) scal[0] = B * 256 + t;
}

// ---------------- 3. compact candidates: prefix16 <= P16 ----------------
__global__ void k_compact(const uint32_t* __restrict__ key, int* __restrict__ scal,
                          unsigned long long* __restrict__ sortbuf) {
  __shared__ int lcnt, lbase;
  int t = threadIdx.x;
  int i = blockIdx.x * blockDim.x + t;
  if (t == 0) lcnt = 0;
  __syncthreads();
  bool sel = false;
  uint32_t kk = 0;
  int my = 0;
  if (i < NN) {
    uint32_t P = (uint32_t)scal[0];
    kk = key[i];
    if ((kk >> 16) <= P) { sel = true; my = atomicAdd(&lcnt, 1); }
  }
  __syncthreads();
  if (t == 0 && lcnt > 0) lbase = atomicAdd(&scal[3], lcnt);
  __syncthreads();
  if (sel) {
    int pos = lbase + my;
    if (pos < SORTN) sortbuf[pos] = (((unsigned long long)kk) << 32) | (uint32_t)i;
  }
}

// ---------------- 4. O(n^2) rank-sort: exact rank = count of strictly-smaller -------
// All real keys are distinct u64 (key32|idx), so count(v' < val) over the
// candidate set is the exact stable rank with the same (score desc, idx asc)
// total order as the old two-level sort. Pads synthesized as ~0ull in the tile
// load; slots [total, KPAD) zero-filled directly. 256 blocks x 32 elems,
// 8 lanes/elem, 16KB LDS tiles, ~1K comparisons per thread.
__global__ void __launch_bounds__(256) k_rank(const unsigned long long* __restrict__ sortbuf,
                                              const int* __restrict__ scal,
                                              const float4* __restrict__ roi,
                                              float4* __restrict__ selbox) {
  __shared__ unsigned long long tile[2048];
  const int t = threadIdx.x;
  int total = scal[3];
  if (total > SORTN) total = SORTN;
  int e = blockIdx.x * 32 + (t >> 3);
  int sub = t & 7;
  bool real = (e < total);
  unsigned long long val = real ? sortbuf[e] : 0ull;
  uint32_t cnt = 0;
  for (int base = 0; base < SORTN; base += 2048) {
    for (int k = t; k < 2048; k += 256) {
      int j = base + k;
      tile[k] = (j < total) ? sortbuf[j] : ~0ull;   // pads never count (< val false)
    }
    __syncthreads();
    if (real) {
      int j0 = sub * 256;
#pragma unroll 8
      for (int k = 0; k < 256; k++)
        cnt += (tile[j0 + k] < val) ? 1u : 0u;
    }
    __syncthreads();
  }
#pragma unroll
  for (int off = 4; off > 0; off >>= 1) cnt += __shfl_xor(cnt, off, 8);
  if (sub == 0) {
    if (real) {
      if (cnt < TOPK) {
        selbox[cnt] = roi[(uint32_t)val];
      } else if (cnt < KPAD) {
        selbox[cnt] = make_float4(0.f, 0.f, 0.f, 0.f);
      }
    } else if (e < KPAD) {
      selbox[e] = make_float4(0.f, 0.f, 0.f, 0.f);  // ranks >= total are exactly these slots
    }
  }
}

// ---------------- 5. mask tiles (256 blocks, grid-stride) + LAST BLOCK greedy keep --
// Verbatim R20 k_maskseq (passed absmax 0 in R20): per-wave readlane tiles,
// 256-atomic handoff, R16 early-exit word-ordered greedy keep tail.
__global__ void __launch_bounds__(256) k_maskseq(const float4* __restrict__ selbox,
                                                 unsigned long long* __restrict__ diag,
                                                 uint32_t* __restrict__ ecnt,
                                                 uint32_t* __restrict__ elist,
                                                 int* __restrict__ scal,
                                                 float* __restrict__ out) {
  __shared__ uint32_t pend32[2 * KW];
  __shared__ uint32_t keep32[2 * KW];
  __shared__ uint32_t wcnt_s[KW], wrank[KW], carry_s;
  __shared__ int lastblk;
  const int t = threadIdx.x, lane = t & 63, wv = t >> 6;

  for (int tile = blockIdx.x * 4 + wv; tile < KW * KW; tile += NBLK * 4) {
    int bi = tile / KW, bj = tile - bi * KW;
    if (bj < bi) continue;
    int i = bi * 64 + lane;
    float4 ibx = selbox[i];
    float4 jbx = selbox[bj * 64 + lane];
    float jaL = (jbx.z - jbx.x) * (jbx.w - jbx.y);
    unsigned long long word = 0;
    if (i < (int)TOPK) {
      float ai = (ibx.z - ibx.x) * (ibx.w - ibx.y);
      for (int jj = 0; jj < 64; jj++) {
        int j = bj * 64 + jj;
        float bxx = rlf(jbx.x, jj), byy = rlf(jbx.y, jj);
        float bzz = rlf(jbx.z, jj), bww = rlf(jbx.w, jj);
        float aj  = rlf(jaL, jj);
        float ltx = fmaxf(ibx.x, bxx), lty = fmaxf(ibx.y, byy);
        float rbx = fminf(ibx.z, bzz), rby = fminf(ibx.w, bww);
        float wx = fmaxf(rbx - ltx, 0.0f), wy = fmaxf(rby - lty, 0.0f);
        float inter = wx * wy;
        float iou = inter / (ai + aj - inter + 1e-9f);
        if (iou > 0.7f && j > i && j < (int)TOPK) word |= (1ull << jj);
      }
    }
    if (bi == bj) {
      diag[i] = word;
    } else {
      uint32_t cnt = (uint32_t)__popcll(word);
      uint32_t pre = cnt;
#pragma unroll
      for (int off = 1; off < 64; off <<= 1) {
        uint32_t v = __shfl_up(pre, off);
        if (lane >= off) pre += v;
      }
      uint32_t total = __shfl(pre, 63);
      if (total != 0) {
        uint32_t excl = pre - cnt;
        uint32_t base2;
        if (lane == 0) base2 = atomicAdd(&ecnt[bi], total);
        base2 = __shfl(base2, 0);
        unsigned long long rem = word;
        uint32_t k = 0;
        while (rem) {
          int jj = (int)__builtin_ctzll(rem);
          rem &= rem - 1;
          uint32_t pos = base2 + excl + k;
          k++;
          if (pos < ECAP2)
            elist[(size_t)bi * ECAP2 + pos] =
                ((uint32_t)(bi * 64 + lane) << 16) | (uint32_t)(bj * 64 + jj);
        }
      }
    }
  }

  __syncthreads();
  if (t == 0) {
    __threadfence();
    uint32_t old = atomicAdd((uint32_t*)&scal[9], 1u);
    lastblk = (old == (uint32_t)(gridDim.x - 1));
  }
  __syncthreads();
  if (!lastblk) return;
  __threadfence();

  if (t < 2 * KW) pend32[t] = 0;
  __syncthreads();

  if (t < 64) {
    uint32_t ec0 = ecnt[lane];
    ec0 = (ec0 > ECAP2) ? ECAP2 : ec0;
    uint32_t ec1 = 0;
    if (64 + lane < KW) {
      ec1 = ecnt[64 + lane];
      ec1 = (ec1 > ECAP2) ? ECAP2 : ec1;
    }
    int V = scal[4];
    if (V > (int)TOPK) V = (int)TOPK;

    unsigned long long mb = diag[lane];
    uint32_t cw = __builtin_amdgcn_readlane(ec0, 0);
    uint32_t en0 = elist[lane];
    uint32_t en1 = elist[64 + lane];

    uint32_t cum2 = 0;
    int cut = KW - 1;
    for (int c = 0; c < KW; c++) {
      unsigned long long mbn = 0;
      uint32_t cwn = 0, en0n = 0, en1n = 0;
      if (c + 1 < KW) {
        mbn = diag[(c + 1) * 64 + lane];
        cwn = (c + 1 < 64) ? __builtin_amdgcn_readlane(ec0, c + 1)
                           : __builtin_amdgcn_readlane(ec1, c + 1 - 64);
        en0n = elist[(size_t)(c + 1) * ECAP2 + lane];
        en1n = elist[(size_t)(c + 1) * ECAP2 + 64 + lane];
      }
      uint32_t plo = pend32[2 * c], phi = pend32[2 * c + 1];
      int d = V - c * 64;
      unsigned long long vinit =
          (d <= 0) ? 0ull : ((d >= 64) ? ~0ull : ((1ull << d) - 1));
      unsigned long long w = vinit & ~(((unsigned long long)phi << 32) | plo);
      unsigned long long sup = __ballot(mb != 0);
      unsigned long long rem = w & sup;
      while (rem) {
        int bb2 = (int)__builtin_ctzll(rem);
        uint32_t mlo = __builtin_amdgcn_readlane((uint32_t)mb, bb2);
        uint32_t mhi = __builtin_amdgcn_readlane((uint32_t)(mb >> 32), bb2);
        w &= ~(((unsigned long long)mhi << 32) | mlo);
        rem = (bb2 >= 63) ? 0ull : (w & sup & (~0ull << (bb2 + 1)));
      }
      if (lane == 0) {
        keep32[2 * c] = (uint32_t)w;
        keep32[2 * c + 1] = (uint32_t)(w >> 32);
      }
      cum2 += (uint32_t)__popcll(w);
      if (cum2 >= OUTK) { cut = c; break; }
      if ((uint32_t)lane < cw) {
        uint32_t i2 = en0 >> 16, j2 = en0 & 0xFFFFu;
        if ((w >> (i2 & 63)) & 1ull) atomicOr(&pend32[j2 >> 5], 1u << (j2 & 31));
      }
      if ((uint32_t)(64 + lane) < cw) {
        uint32_t i2 = en1 >> 16, j2 = en1 & 0xFFFFu;
        if ((w >> (i2 & 63)) & 1ull) atomicOr(&pend32[j2 >> 5], 1u << (j2 & 31));
      }
      for (uint32_t k = 128 + (uint32_t)lane; k < cw; k += 64) {
        uint32_t e = elist[(size_t)c * ECAP2 + k];
        uint32_t i2 = e >> 16, j2 = e & 0xFFFFu;
        if ((w >> (i2 & 63)) & 1ull) atomicOr(&pend32[j2 >> 5], 1u << (j2 & 31));
      }
      mb = mbn; cw = cwn; en0 = en0n; en1 = en1n;
    }
    for (int wz = cut + 1 + lane; wz < KW; wz += 64) {
      keep32[2 * wz] = 0;
      keep32[2 * wz + 1] = 0;
    }
  }
  __syncthreads();

  if (t < KW)
    wcnt_s[t] = (uint32_t)(__popc(keep32[2 * t]) + __popc(keep32[2 * t + 1]));
  __syncthreads();
  if (t < 64) {
    uint32_t v = wcnt_s[t], p2 = v;
#pragma unroll
    for (int off = 1; off < 64; off <<= 1) {
      uint32_t x = __shfl_up(p2, off);
      if (lane >= off) p2 += x;
    }
    wrank[t] = p2 - v;
    if (t == 63) carry_s = p2;
  }
  __syncthreads();
  if (t >= 64 && t < KW) {
    uint32_t v = wcnt_s[t], p2 = v;
#pragma unroll
    for (int off = 1; off < 64; off <<= 1) {
      uint32_t x = __shfl_up(p2, off);
      if (lane >= off) p2 += x;
    }
    wrank[t] = carry_s + p2 - v;
  }
  __syncthreads();
  for (int o = t; o < OUTK * 4; o += 256) out[o] = 0.0f;
  __syncthreads();
  for (int r = t; r < (int)TOPK; r += 256) {
    unsigned long long w =
        ((unsigned long long)keep32[2 * (r >> 6) + 1] << 32) | keep32[2 * (r >> 6)];
    int bb2 = r & 63;
    if ((w >> bb2) & 1ull) {
      uint32_t rank = wrank[r >> 6] + (uint32_t)__popcll(w & ((1ull << bb2) - 1ull));
      if (rank < OUTK) {
        float4 bx = selbox[r];
        out[rank * 4 + 0] = bx.x;
        out[rank * 4 + 1] = bx.y;
        out[rank * 4 + 2] = bx.z;
        out[rank * 4 + 3] = bx.w;
      }
    }
  }
}

// ---------------- launch ----------------
extern "C" void kernel_launch(void* const* d_in, const int* in_sizes, int n_in,
                              void* d_out, int out_size, void* d_ws, size_t ws_size,
                              hipStream_t stream) {
  const float* cls    = (const float*)d_in[0];
  const float* reg    = (const float*)d_in[1];
  const float* anchor = (const float*)d_in[2];
  float* out = (float*)d_out;
  char* ws = (char*)d_ws;

  float4*   roi     = (float4*)(ws + OFF_ROI);
  uint32_t* key     = (uint32_t*)(ws + OFF_KEY);
  uint32_t* hist16  = (uint32_t*)(ws + OFF_HIST16);
  uint32_t* hists   = (uint32_t*)(ws + OFF_HISTS);
  uint32_t* bsum    = (uint32_t*)(ws + OFF_BSUM);
  int*      scal    = (int*)(ws + OFF_SCAL);
  uint32_t* ecnt    = (uint32_t*)(ws + OFF_ECNT);
  unsigned long long* sortbuf = (unsigned long long*)(ws + OFF_SORT);
  float4*   selbox  = (float4*)(ws + OFF_SELBOX);
  unsigned long long* diag = (unsigned long long*)(ws + OFF_DIAG);
  uint32_t* elist   = (uint32_t*)(ws + OFF_ELIST);

  int blocks = (NN + 255) / 256;
  k_init<<<INIT_BLOCKS, 256, 0, stream>>>(ws);
  k_decode<<<blocks, 256, 0, stream>>>(cls, reg, anchor, roi, key, hist16);
  k_hsumS<<<NBLK, 256, 0, stream>>>(hist16, hists, bsum, scal);
  k_compact<<<blocks, 256, 0, stream>>>(key, scal, sortbuf);
  k_rank<<<SORTN / 32, 256, 0, stream>>>(sortbuf, scal, roi, selbox);
  k_maskseq<<<NBLK, 256, 0, stream>>>(selbox, diag, ecnt, elist, scal, out);
}

// Round 24
// 113.159 us; speedup vs baseline: 1.2050x; 1.2050x over previous
//
#include <hip/hip_runtime.h>
#include <stdint.h>

#pragma clang fp contract(off)

#define NN    300000
#define TOPK  6000u
#define KW    94
#define KPAD  6016
#define SORTN 8192
#define OUTK  300
#define ECAP2 2048
#define NREP  8
#define NBLK  256

// ---------------- workspace layout (bytes) ----------------
static constexpr size_t OFF_ROI    = 0;                                   // NN*16
static constexpr size_t OFF_KEY    = OFF_ROI + (size_t)NN * 16;           // NN*4
static constexpr size_t OFF_HIST16 = ((OFF_KEY + (size_t)NN * 4 + 255) & ~(size_t)255); // NREP*65536*4
static constexpr size_t OFF_SCAL   = OFF_HIST16 + (size_t)NREP * 65536 * 4; // 256 B
static constexpr size_t OFF_ECNT   = OFF_SCAL + 256;                      // 94*4 pad 512
static constexpr size_t ZERO_BYTES = (OFF_ECNT + 512) - OFF_HIST16;
static constexpr size_t OFF_HISTS  = OFF_ECNT + 512;                      // 65536*4
static constexpr size_t OFF_BSUM   = OFF_HISTS + 65536 * 4;               // 256*4 pad 1024
static constexpr size_t OFF_SORT   = OFF_BSUM + 1024;                     // SORTN*8
static constexpr size_t OFF_SELBOX = OFF_SORT + (size_t)SORTN * 8;        // KPAD*16
static constexpr size_t OFF_DIAG   = ((OFF_SELBOX + (size_t)KPAD * 16 + 255) & ~(size_t)255); // KPAD*8
static constexpr size_t OFF_ELIST  = OFF_DIAG + (size_t)KPAD * 8;         // KW*ECAP2*4

// scal[]: [0]=P16 bin, [3]=compact counter, [4]=valid total, [8]=hsum done ctr

static constexpr uint32_t ZG = (uint32_t)(ZERO_BYTES / 16);
static constexpr uint32_t INIT_BLOCKS = (ZG + 255) / 256;

__device__ __forceinline__ uint32_t score_key(float s) {
  uint32_t u = __float_as_uint(s);
  u = (u >> 31) ? ~u : (u | 0x80000000u);
  return ~u;
}
__device__ __forceinline__ uint32_t hslot(uint32_t b) { return __brev(b) >> 16; }

// ---------------- 0. workspace init (hist replicas + scal + ecnt) ----------------
__global__ void __launch_bounds__(256) k_init(char* __restrict__ ws) {
  uint32_t idx = blockIdx.x * 256 + threadIdx.x;
  if (idx < ZG)
    ((uint4*)(ws + OFF_HIST16))[idx] = make_uint4(0u, 0u, 0u, 0u);
}

// ---------------- 1. decode + key + replicated 16-bit histogram ----------------
__global__ void k_decode(const float* __restrict__ cls, const float* __restrict__ reg,
                         const float* __restrict__ anchor, float4* __restrict__ roi,
                         uint32_t* __restrict__ key, uint32_t* __restrict__ hist16) {
  int i = blockIdx.x * blockDim.x + threadIdx.x;
  if (i >= NN) return;
  float c0 = cls[2 * i], c1 = cls[2 * i + 1];
  float m  = fmaxf(c0, c1);
  float a0 = c0 - m, a1 = c1 - m;
  float tn = fminf(a0, a1);
  float e  = (float)exp((double)tn);
  float e0 = (a0 == 0.0f) ? 1.0f : e;
  float e1 = (a1 == 0.0f) ? 1.0f : e;
  float s  = e1 / (e0 + e1);

  float4 a = ((const float4*)anchor)[i];
  float acx = (a.x + a.z) * 0.5f;
  float acy = (a.y + a.w) * 0.5f;
  float aw  = a.z - a.x;
  float ah  = a.w - a.y;
  float4 r = ((const float4*)reg)[i];
  float cx = r.x * aw + acx;
  float cy = r.y * ah + acy;
  float w  = (float)exp((double)r.z) * aw;
  float h  = (float)exp((double)r.w) * ah;
  float x1 = cx - w * 0.5f, y1 = cy - h * 0.5f;
  float x2 = cx + w * 0.5f, y2 = cy + h * 0.5f;
  x1 = fminf(fmaxf(x1, 0.0f), 1.0f);
  y1 = fminf(fmaxf(y1, 0.0f), 1.0f);
  x2 = fminf(fmaxf(x2, 0.0f), 1.0f);
  y2 = fminf(fmaxf(y2, 0.0f), 1.0f);
  float ws_ = x2 - x1, hs_ = y2 - y1;
  bool valid = (hs_ >= 0.001f) && (ws_ >= 0.001f);
  float msc = valid ? s : -__builtin_inff();
  uint32_t kk = score_key(msc);

  roi[i] = make_float4(x1, y1, x2, y2);
  key[i] = kk;
  if (valid) atomicAdd(&hist16[((blockIdx.x & (NREP - 1)) << 16) + hslot(kk >> 16)], 1u);
}

// ---------------- 2. hsum (256 blocks) + LAST BLOCK runs hierarchical scan --------
__global__ void __launch_bounds__(256) k_hsumS(const uint32_t* __restrict__ hist16,
                                               uint32_t* __restrict__ hists,
                                               uint32_t* __restrict__ bsum,
                                               int* __restrict__ scal) {
  __shared__ uint32_t red[256];
  __shared__ uint32_t cum[256];
  __shared__ int Bs;
  __shared__ int lastblk;
  int t = threadIdx.x;
  int b = blockIdx.x * 256 + t;
  uint32_t slot = hslot((uint32_t)b);
  uint32_t s = 0;
#pragma unroll
  for (int r = 0; r < NREP; r++) s += hist16[(r << 16) + slot];
  hists[b] = s;
  red[t] = s;
  __syncthreads();
  for (int off = 128; off > 0; off >>= 1) {
    if (t < off) red[t] += red[t + off];
    __syncthreads();
  }
  if (t == 0) bsum[blockIdx.x] = red[0];

  __syncthreads();
  if (t == 0) {
    __threadfence();
    uint32_t old = atomicAdd((uint32_t*)&scal[8], 1u);
    lastblk = (old == (uint32_t)(gridDim.x - 1));
  }
  __syncthreads();
  if (!lastblk) return;
  __threadfence();

  uint32_t v = bsum[t];
  cum[t] = v;
  if (t == 0) Bs = 256;
  __syncthreads();
  for (int off = 1; off < 256; off <<= 1) {
    uint32_t x = (t >= off) ? cum[t - off] : 0;
    __syncthreads();
    cum[t] += x;
    __syncthreads();
  }
  if (t == 255) scal[4] = (int)cum[255];
  if (cum[t] >= TOPK && (t == 0 || cum[t - 1] < TOPK)) Bs = t;
  __syncthreads();
  int B = Bs;
  if (B == 256) { if (t == 0) scal[0] = 65535; return; }
  uint32_t cumbase = (B > 0) ? cum[B - 1] : 0;
  __syncthreads();
  uint32_t h2 = hists[B * 256 + t];
  cum[t] = h2;
  __syncthreads();
  for (int off = 1; off < 256; off <<= 1) {
    uint32_t x = (t >= off) ? cum[t - off] : 0;
    __syncthreads();
    cum[t] += x;
    __syncthreads();
  }
  uint32_t cc = cumbase + cum[t];
  uint32_t cp = cc - h2;
  if (cc >= TOPK && cp < TOPK) scal[0] = B * 256 + t;
}

// ---------------- 3. compact candidates: prefix16 <= P16 ----------------
__global__ void k_compact(const uint32_t* __restrict__ key, int* __restrict__ scal,
                          unsigned long long* __restrict__ sortbuf) {
  __shared__ int lcnt, lbase;
  int t = threadIdx.x;
  int i = blockIdx.x * blockDim.x + t;
  if (t == 0) lcnt = 0;
  __syncthreads();
  bool sel = false;
  uint32_t kk = 0;
  int my = 0;
  if (i < NN) {
    uint32_t P = (uint32_t)scal[0];
    kk = key[i];
    if ((kk >> 16) <= P) { sel = true; my = atomicAdd(&lcnt, 1); }
  }
  __syncthreads();
  if (t == 0 && lcnt > 0) lbase = atomicAdd(&scal[3], lcnt);
  __syncthreads();
  if (sel) {
    int pos = lbase + my;
    if (pos < SORTN) sortbuf[pos] = (((unsigned long long)kk) << 32) | (uint32_t)i;
  }
}

// ---------------- 4. O(n^2) rank-sort (R23-validated): rank = count strictly-smaller
// Works on compact's UNSORTED output; all real keys distinct u64 => exact
// stable rank, same (score desc, idx asc) order. Pads ~0ull in tile load;
// slots [total, KPAD) zero-filled via the e>=total branch.
__global__ void __launch_bounds__(256) k_rank(const unsigned long long* __restrict__ sortbuf,
                                              const int* __restrict__ scal,
                                              const float4* __restrict__ roi,
                                              float4* __restrict__ selbox) {
  __shared__ unsigned long long tile[2048];
  const int t = threadIdx.x;
  int total = scal[3];
  if (total > SORTN) total = SORTN;
  int e = blockIdx.x * 32 + (t >> 3);
  int sub = t & 7;
  bool real = (e < total);
  unsigned long long val = real ? sortbuf[e] : 0ull;
  uint32_t cnt = 0;
  for (int base = 0; base < SORTN; base += 2048) {
    for (int k = t; k < 2048; k += 256) {
      int j = base + k;
      tile[k] = (j < total) ? sortbuf[j] : ~0ull;
    }
    __syncthreads();
    if (real) {
      int j0 = sub * 256;
#pragma unroll 8
      for (int k = 0; k < 256; k++)
        cnt += (tile[j0 + k] < val) ? 1u : 0u;
    }
    __syncthreads();
  }
#pragma unroll
  for (int off = 4; off > 0; off >>= 1) cnt += __shfl_xor(cnt, off, 8);
  if (sub == 0) {
    if (real) {
      if (cnt < TOPK) {
        selbox[cnt] = roi[(uint32_t)val];
      } else if (cnt < KPAD) {
        selbox[cnt] = make_float4(0.f, 0.f, 0.f, 0.f);
      }
    } else if (e < KPAD) {
      selbox[e] = make_float4(0.f, 0.f, 0.f, 0.f);
    }
  }
}

// ---------------- 5. suppression: dense diag + per-word global entry lists (R22) ----
__global__ void __launch_bounds__(64) k_mask(const float4* __restrict__ selbox,
                                             unsigned long long* __restrict__ diag,
                                             uint32_t* __restrict__ ecnt,
                                             uint32_t* __restrict__ elist) {
  int bi = blockIdx.x, bj = blockIdx.y;
  if (bj < bi) return;
  int t = threadIdx.x;
  __shared__ float4 jb[64];
  __shared__ float  ja[64];
  int j0 = bj * 64;
  float4 cb = selbox[j0 + t];
  jb[t] = cb;
  ja[t] = (cb.z - cb.x) * (cb.w - cb.y);
  __syncthreads();
  int i = bi * 64 + t;
  unsigned long long word = 0;
  if (i < (int)TOPK) {
    float4 bi4 = selbox[i];
    float ai = (bi4.z - bi4.x) * (bi4.w - bi4.y);
    for (int jj = 0; jj < 64; jj++) {
      int j = j0 + jj;
      float4 bb = jb[jj];
      float ltx = fmaxf(bi4.x, bb.x), lty = fmaxf(bi4.y, bb.y);
      float rbx = fminf(bi4.z, bb.z), rby = fminf(bi4.w, bb.w);
      float wx = fmaxf(rbx - ltx, 0.0f), wy = fmaxf(rby - lty, 0.0f);
      float inter = wx * wy;
      float iou = inter / (ai + ja[jj] - inter + 1e-9f);
      if (iou > 0.7f && j > i && j < (int)TOPK) word |= (1ull << jj);
    }
  }
  if (bi == bj) {
    diag[i] = word;
    return;
  }
  uint32_t cnt = (uint32_t)__popcll(word);
  uint32_t pre = cnt;
#pragma unroll
  for (int off = 1; off < 64; off <<= 1) {
    uint32_t v = __shfl_up(pre, off);
    if (t >= off) pre += v;
  }
  uint32_t total = __shfl(pre, 63);
  if (total == 0) return;
  uint32_t excl = pre - cnt;
  uint32_t base;
  if (t == 0) base = atomicAdd(&ecnt[bi], total);
  base = __shfl(base, 0);
  unsigned long long rem = word;
  uint32_t k = 0;
  while (rem) {
    int jj = (int)__builtin_ctzll(rem);
    rem &= rem - 1;
    uint32_t pos = base + excl + k;
    k++;
    if (pos < ECAP2) elist[(size_t)bi * ECAP2 + pos] = ((uint32_t)i << 16) | (uint32_t)(j0 + jj);
  }
}

// ---------------- 6. greedy keep: word-ordered pass, early exit (R16/R22 verbatim) --
__global__ void __launch_bounds__(256) k_seq(const unsigned long long* __restrict__ diag,
                                             const uint32_t* __restrict__ ecnt,
                                             const uint32_t* __restrict__ elist,
                                             const int* __restrict__ scal,
                                             const float4* __restrict__ selbox,
                                             float* __restrict__ out) {
  __shared__ uint32_t pend32[2 * KW];
  __shared__ uint32_t keep32[2 * KW];
  __shared__ uint32_t wcnt_s[KW], wrank[KW], carry_s;
  const int t = threadIdx.x, lane = t & 63;

  if (t < 2 * KW) pend32[t] = 0;
  __syncthreads();

  if (t < 64) {
    uint32_t ec0 = ecnt[lane];
    ec0 = (ec0 > ECAP2) ? ECAP2 : ec0;
    uint32_t ec1 = 0;
    if (64 + lane < KW) {
      ec1 = ecnt[64 + lane];
      ec1 = (ec1 > ECAP2) ? ECAP2 : ec1;
    }
    int V = scal[4];
    if (V > (int)TOPK) V = (int)TOPK;

    unsigned long long mb = diag[lane];
    uint32_t cw = __builtin_amdgcn_readlane(ec0, 0);
    uint32_t en0 = elist[lane];
    uint32_t en1 = elist[64 + lane];

    uint32_t cum = 0;
    int cut = KW - 1;
    for (int c = 0; c < KW; c++) {
      unsigned long long mbn = 0;
      uint32_t cwn = 0, en0n = 0, en1n = 0;
      if (c + 1 < KW) {
        mbn = diag[(c + 1) * 64 + lane];
        cwn = (c + 1 < 64) ? __builtin_amdgcn_readlane(ec0, c + 1)
                           : __builtin_amdgcn_readlane(ec1, c + 1 - 64);
        en0n = elist[(size_t)(c + 1) * ECAP2 + lane];
        en1n = elist[(size_t)(c + 1) * ECAP2 + 64 + lane];
      }
      uint32_t plo = pend32[2 * c], phi = pend32[2 * c + 1];
      int d = V - c * 64;
      unsigned long long vinit =
          (d <= 0) ? 0ull : ((d >= 64) ? ~0ull : ((1ull << d) - 1));
      unsigned long long w = vinit & ~(((unsigned long long)phi << 32) | plo);
      unsigned long long sup = __ballot(mb != 0);
      unsigned long long rem = w & sup;
      while (rem) {
        int b = (int)__builtin_ctzll(rem);
        uint32_t mlo = __builtin_amdgcn_readlane((uint32_t)mb, b);
        uint32_t mhi = __builtin_amdgcn_readlane((uint32_t)(mb >> 32), b);
        w &= ~(((unsigned long long)mhi << 32) | mlo);
        rem = (b >= 63) ? 0ull : (w & sup & (~0ull << (b + 1)));
      }
      if (lane == 0) {
        keep32[2 * c] = (uint32_t)w;
        keep32[2 * c + 1] = (uint32_t)(w >> 32);
      }
      cum += (uint32_t)__popcll(w);
      if (cum >= OUTK) { cut = c; break; }
      if ((uint32_t)lane < cw) {
        uint32_t i = en0 >> 16, j = en0 & 0xFFFFu;
        if ((w >> (i & 63)) & 1ull) atomicOr(&pend32[j >> 5], 1u << (j & 31));
      }
      if ((uint32_t)(64 + lane) < cw) {
        uint32_t i = en1 >> 16, j = en1 & 0xFFFFu;
        if ((w >> (i & 63)) & 1ull) atomicOr(&pend32[j >> 5], 1u << (j & 31));
      }
      for (uint32_t k = 128 + (uint32_t)lane; k < cw; k += 64) {
        uint32_t e = elist[(size_t)c * ECAP2 + k];
        uint32_t i = e >> 16, j = e & 0xFFFFu;
        if ((w >> (i & 63)) & 1ull) atomicOr(&pend32[j >> 5], 1u << (j & 31));
      }
      mb = mbn; cw = cwn; en0 = en0n; en1 = en1n;
    }
    for (int wz = cut + 1 + lane; wz < KW; wz += 64) {
      keep32[2 * wz] = 0;
      keep32[2 * wz + 1] = 0;
    }
  }
  __syncthreads();

  if (t < KW)
    wcnt_s[t] = (uint32_t)(__popc(keep32[2 * t]) + __popc(keep32[2 * t + 1]));
  __syncthreads();
  if (t < 64) {
    uint32_t v = wcnt_s[t], p2 = v;
#pragma unroll
    for (int off = 1; off < 64; off <<= 1) {
      uint32_t x = __shfl_up(p2, off);
      if (lane >= off) p2 += x;
    }
    wrank[t] = p2 - v;
    if (t == 63) carry_s = p2;
  }
  __syncthreads();
  if (t >= 64 && t < KW) {
    uint32_t v = wcnt_s[t], p2 = v;
#pragma unroll
    for (int off = 1; off < 64; off <<= 1) {
      uint32_t x = __shfl_up(p2, off);
      if (lane >= off) p2 += x;
    }
    wrank[t] = carry_s + p2 - v;
  }
  __syncthreads();
  for (int o = t; o < OUTK * 4; o += 256) out[o] = 0.0f;
  __syncthreads();
  for (int r = t; r < (int)TOPK; r += 256) {
    unsigned long long w =
        ((unsigned long long)keep32[2 * (r >> 6) + 1] << 32) | keep32[2 * (r >> 6)];
    int b = r & 63;
    if ((w >> b) & 1ull) {
      uint32_t rank = wrank[r >> 6] + (uint32_t)__popcll(w & ((1ull << b) - 1ull));
      if (rank < OUTK) {
        float4 bx = selbox[r];
        out[rank * 4 + 0] = bx.x;
        out[rank * 4 + 1] = bx.y;
        out[rank * 4 + 2] = bx.z;
        out[rank * 4 + 3] = bx.w;
      }
    }
  }
}

// ---------------- launch ----------------
extern "C" void kernel_launch(void* const* d_in, const int* in_sizes, int n_in,
                              void* d_out, int out_size, void* d_ws, size_t ws_size,
                              hipStream_t stream) {
  const float* cls    = (const float*)d_in[0];
  const float* reg    = (const float*)d_in[1];
  const float* anchor = (const float*)d_in[2];
  float* out = (float*)d_out;
  char* ws = (char*)d_ws;

  float4*   roi     = (float4*)(ws + OFF_ROI);
  uint32_t* key     = (uint32_t*)(ws + OFF_KEY);
  uint32_t* hist16  = (uint32_t*)(ws + OFF_HIST16);
  uint32_t* hists   = (uint32_t*)(ws + OFF_HISTS);
  uint32_t* bsum    = (uint32_t*)(ws + OFF_BSUM);
  int*      scal    = (int*)(ws + OFF_SCAL);
  uint32_t* ecnt    = (uint32_t*)(ws + OFF_ECNT);
  unsigned long long* sortbuf = (unsigned long long*)(ws + OFF_SORT);
  float4*   selbox  = (float4*)(ws + OFF_SELBOX);
  unsigned long long* diag = (unsigned long long*)(ws + OFF_DIAG);
  uint32_t* elist   = (uint32_t*)(ws + OFF_ELIST);

  int blocks = (NN + 255) / 256;
  k_init<<<INIT_BLOCKS, 256, 0, stream>>>(ws);
  k_decode<<<blocks, 256, 0, stream>>>(cls, reg, anchor, roi, key, hist16);
  k_hsumS<<<NBLK, 256, 0, stream>>>(hist16, hists, bsum, scal);
  k_compact<<<blocks, 256, 0, stream>>>(key, scal, sortbuf);
  k_rank<<<SORTN / 32, 256, 0, stream>>>(sortbuf, scal, roi, selbox);
  k_mask<<<dim3(KW, KW), 64, 0, stream>>>(selbox, diag, ecnt, elist);
  k_seq<<<1, 256, 0, stream>>>(diag, ecnt, elist, scal, selbox, out);
}

// Round 25
// 99.502 us; speedup vs baseline: 1.3704x; 1.1373x over previous
//
#include <hip/hip_runtime.h>
#include <stdint.h>

#pragma clang fp contract(off)

#define NN    300000
#define TOPK  6000u
#define KW    94
#define KPAD  6016
#define SORTN 8192
#define OUTK  300
#define ECAP2 2048
#define NREP  8
#define NBLK  256

// ---------------- workspace layout (bytes) ----------------
static constexpr size_t OFF_ROI    = 0;                                   // NN*16
static constexpr size_t OFF_KEY    = OFF_ROI + (size_t)NN * 16;           // NN*4
static constexpr size_t OFF_HIST16 = ((OFF_KEY + (size_t)NN * 4 + 255) & ~(size_t)255); // NREP*65536*4
static constexpr size_t OFF_SCAL   = OFF_HIST16 + (size_t)NREP * 65536 * 4; // 256 B
static constexpr size_t OFF_ECNT   = OFF_SCAL + 256;                      // 94*4 pad 512
static constexpr size_t ZERO_BYTES = (OFF_ECNT + 512) - OFF_HIST16;
static constexpr size_t OFF_HISTS  = OFF_ECNT + 512;                      // 65536*4
static constexpr size_t OFF_BSUM   = OFF_HISTS + 65536 * 4;               // 256*4 pad 1024
static constexpr size_t OFF_SORT   = OFF_BSUM + 1024;                     // SORTN*8
static constexpr size_t OFF_SELBOX = OFF_SORT + (size_t)SORTN * 8;        // KPAD*16
static constexpr size_t OFF_DIAG   = ((OFF_SELBOX + (size_t)KPAD * 16 + 255) & ~(size_t)255); // KPAD*8
static constexpr size_t OFF_ELIST  = OFF_DIAG + (size_t)KPAD * 8;         // KW*ECAP2*4

// scal[]: [0]=P16 bin, [3]=compact counter, [4]=valid total, [8]=hsum done ctr

static constexpr uint32_t ZG = (uint32_t)(ZERO_BYTES / 16);
static constexpr uint32_t INIT_BLOCKS = (ZG + 255) / 256;

__device__ __forceinline__ uint32_t score_key(float s) {
  uint32_t u = __float_as_uint(s);
  u = (u >> 31) ? ~u : (u | 0x80000000u);
  return ~u;
}
__device__ __forceinline__ uint32_t hslot(uint32_t b) { return __brev(b) >> 16; }

// ---------------- 0. workspace init (hist replicas + scal + ecnt) ----------------
__global__ void __launch_bounds__(256) k_init(char* __restrict__ ws) {
  uint32_t idx = blockIdx.x * 256 + threadIdx.x;
  if (idx < ZG)
    ((uint4*)(ws + OFF_HIST16))[idx] = make_uint4(0u, 0u, 0u, 0u);
}

// ---------------- 1. decode + key + replicated 16-bit histogram ----------------
__global__ void k_decode(const float* __restrict__ cls, const float* __restrict__ reg,
                         const float* __restrict__ anchor, float4* __restrict__ roi,
                         uint32_t* __restrict__ key, uint32_t* __restrict__ hist16) {
  int i = blockIdx.x * blockDim.x + threadIdx.x;
  if (i >= NN) return;
  float c0 = cls[2 * i], c1 = cls[2 * i + 1];
  float m  = fmaxf(c0, c1);
  float a0 = c0 - m, a1 = c1 - m;
  float tn = fminf(a0, a1);
  float e  = (float)exp((double)tn);
  float e0 = (a0 == 0.0f) ? 1.0f : e;
  float e1 = (a1 == 0.0f) ? 1.0f : e;
  float s  = e1 / (e0 + e1);

  float4 a = ((const float4*)anchor)[i];
  float acx = (a.x + a.z) * 0.5f;
  float acy = (a.y + a.w) * 0.5f;
  float aw  = a.z - a.x;
  float ah  = a.w - a.y;
  float4 r = ((const float4*)reg)[i];
  float cx = r.x * aw + acx;
  float cy = r.y * ah + acy;
  float w  = (float)exp((double)r.z) * aw;
  float h  = (float)exp((double)r.w) * ah;
  float x1 = cx - w * 0.5f, y1 = cy - h * 0.5f;
  float x2 = cx + w * 0.5f, y2 = cy + h * 0.5f;
  x1 = fminf(fmaxf(x1, 0.0f), 1.0f);
  y1 = fminf(fmaxf(y1, 0.0f), 1.0f);
  x2 = fminf(fmaxf(x2, 0.0f), 1.0f);
  y2 = fminf(fmaxf(y2, 0.0f), 1.0f);
  float ws_ = x2 - x1, hs_ = y2 - y1;
  bool valid = (hs_ >= 0.001f) && (ws_ >= 0.001f);
  float msc = valid ? s : -__builtin_inff();
  uint32_t kk = score_key(msc);

  roi[i] = make_float4(x1, y1, x2, y2);
  key[i] = kk;
  if (valid) atomicAdd(&hist16[((blockIdx.x & (NREP - 1)) << 16) + hslot(kk >> 16)], 1u);
}

// ---------------- 2. hsum (256 blocks) + LAST BLOCK runs hierarchical scan --------
__global__ void __launch_bounds__(256) k_hsumS(const uint32_t* __restrict__ hist16,
                                               uint32_t* __restrict__ hists,
                                               uint32_t* __restrict__ bsum,
                                               int* __restrict__ scal) {
  __shared__ uint32_t red[256];
  __shared__ uint32_t cum[256];
  __shared__ int Bs;
  __shared__ int lastblk;
  int t = threadIdx.x;
  int b = blockIdx.x * 256 + t;
  uint32_t slot = hslot((uint32_t)b);
  uint32_t s = 0;
#pragma unroll
  for (int r = 0; r < NREP; r++) s += hist16[(r << 16) + slot];
  hists[b] = s;
  red[t] = s;
  __syncthreads();
  for (int off = 128; off > 0; off >>= 1) {
    if (t < off) red[t] += red[t + off];
    __syncthreads();
  }
  if (t == 0) bsum[blockIdx.x] = red[0];

  __syncthreads();
  if (t == 0) {
    __threadfence();
    uint32_t old = atomicAdd((uint32_t*)&scal[8], 1u);
    lastblk = (old == (uint32_t)(gridDim.x - 1));
  }
  __syncthreads();
  if (!lastblk) return;
  __threadfence();

  uint32_t v = bsum[t];
  cum[t] = v;
  if (t == 0) Bs = 256;
  __syncthreads();
  for (int off = 1; off < 256; off <<= 1) {
    uint32_t x = (t >= off) ? cum[t - off] : 0;
    __syncthreads();
    cum[t] += x;
    __syncthreads();
  }
  if (t == 255) scal[4] = (int)cum[255];
  if (cum[t] >= TOPK && (t == 0 || cum[t - 1] < TOPK)) Bs = t;
  __syncthreads();
  int B = Bs;
  if (B == 256) { if (t == 0) scal[0] = 65535; return; }
  uint32_t cumbase = (B > 0) ? cum[B - 1] : 0;
  __syncthreads();
  uint32_t h2 = hists[B * 256 + t];
  cum[t] = h2;
  __syncthreads();
  for (int off = 1; off < 256; off <<= 1) {
    uint32_t x = (t >= off) ? cum[t - off] : 0;
    __syncthreads();
    cum[t] += x;
    __syncthreads();
  }
  uint32_t cc = cumbase + cum[t];
  uint32_t cp = cc - h2;
  if (cc >= TOPK && cp < TOPK) scal[0] = B * 256 + t;
}

// ---------------- 3. compact candidates: prefix16 <= P16 ----------------
__global__ void k_compact(const uint32_t* __restrict__ key, int* __restrict__ scal,
                          unsigned long long* __restrict__ sortbuf) {
  __shared__ int lcnt, lbase;
  int t = threadIdx.x;
  int i = blockIdx.x * blockDim.x + t;
  if (t == 0) lcnt = 0;
  __syncthreads();
  bool sel = false;
  uint32_t kk = 0;
  int my = 0;
  if (i < NN) {
    uint32_t P = (uint32_t)scal[0];
    kk = key[i];
    if ((kk >> 16) <= P) { sel = true; my = atomicAdd(&lcnt, 1); }
  }
  __syncthreads();
  if (t == 0 && lcnt > 0) lbase = atomicAdd(&scal[3], lcnt);
  __syncthreads();
  if (sel) {
    int pos = lbase + my;
    if (pos < SORTN) sortbuf[pos] = (((unsigned long long)kk) << 32) | (uint32_t)i;
  }
}

// ---------------- 4. O(n^2) rank-sort, BANK-CONFLICT-FREE interleaved counting ------
// rank = count of strictly-smaller keys (all real keys distinct u64 => exact
// stable rank, same (score desc, idx asc) order). Lane sub counts elements
// tile[8*k2+sub]: at fixed k2 the wave's 8 distinct addresses span banks
// 2*sub+16*k2 (conflict-free; same-address across element-groups broadcasts).
// R24's tile[sub*256+k] put all 8 addresses in ONE bank (8-way, ~3x).
__global__ void __launch_bounds__(256) k_rank(const unsigned long long* __restrict__ sortbuf,
                                              const int* __restrict__ scal,
                                              const float4* __restrict__ roi,
                                              float4* __restrict__ selbox) {
  __shared__ unsigned long long tile[2048];
  const int t = threadIdx.x;
  int total = scal[3];
  if (total > SORTN) total = SORTN;
  int e = blockIdx.x * 32 + (t >> 3);
  int sub = t & 7;
  bool real = (e < total);
  unsigned long long val = real ? sortbuf[e] : 0ull;
  uint32_t cnt = 0;
  for (int base = 0; base < SORTN; base += 2048) {
    for (int k = t; k < 2048; k += 256) {
      int j = base + k;
      tile[k] = (j < total) ? sortbuf[j] : ~0ull;
    }
    __syncthreads();
    if (real) {
#pragma unroll 8
      for (int k2 = 0; k2 < 256; k2++)
        cnt += (tile[(k2 << 3) + sub] < val) ? 1u : 0u;
    }
    __syncthreads();
  }
#pragma unroll
  for (int off = 4; off > 0; off >>= 1) cnt += __shfl_xor(cnt, off, 8);
  if (sub == 0) {
    if (real) {
      if (cnt < TOPK) {
        selbox[cnt] = roi[(uint32_t)val];
      } else if (cnt < KPAD) {
        selbox[cnt] = make_float4(0.f, 0.f, 0.f, 0.f);
      }
    } else if (e < KPAD) {
      selbox[e] = make_float4(0.f, 0.f, 0.f, 0.f);
    }
  }
}

// ---------------- 5. suppression: dense diag + per-word global entry lists (R22) ----
__global__ void __launch_bounds__(64) k_mask(const float4* __restrict__ selbox,
                                             unsigned long long* __restrict__ diag,
                                             uint32_t* __restrict__ ecnt,
                                             uint32_t* __restrict__ elist) {
  int bi = blockIdx.x, bj = blockIdx.y;
  if (bj < bi) return;
  int t = threadIdx.x;
  __shared__ float4 jb[64];
  __shared__ float  ja[64];
  int j0 = bj * 64;
  float4 cb = selbox[j0 + t];
  jb[t] = cb;
  ja[t] = (cb.z - cb.x) * (cb.w - cb.y);
  __syncthreads();
  int i = bi * 64 + t;
  unsigned long long word = 0;
  if (i < (int)TOPK) {
    float4 bi4 = selbox[i];
    float ai = (bi4.z - bi4.x) * (bi4.w - bi4.y);
    for (int jj = 0; jj < 64; jj++) {
      int j = j0 + jj;
      float4 bb = jb[jj];
      float ltx = fmaxf(bi4.x, bb.x), lty = fmaxf(bi4.y, bb.y);
      float rbx = fminf(bi4.z, bb.z), rby = fminf(bi4.w, bb.w);
      float wx = fmaxf(rbx - ltx, 0.0f), wy = fmaxf(rby - lty, 0.0f);
      float inter = wx * wy;
      float iou = inter / (ai + ja[jj] - inter + 1e-9f);
      if (iou > 0.7f && j > i && j < (int)TOPK) word |= (1ull << jj);
    }
  }
  if (bi == bj) {
    diag[i] = word;
    return;
  }
  uint32_t cnt = (uint32_t)__popcll(word);
  uint32_t pre = cnt;
#pragma unroll
  for (int off = 1; off < 64; off <<= 1) {
    uint32_t v = __shfl_up(pre, off);
    if (t >= off) pre += v;
  }
  uint32_t total = __shfl(pre, 63);
  if (total == 0) return;
  uint32_t excl = pre - cnt;
  uint32_t base;
  if (t == 0) base = atomicAdd(&ecnt[bi], total);
  base = __shfl(base, 0);
  unsigned long long rem = word;
  uint32_t k = 0;
  while (rem) {
    int jj = (int)__builtin_ctzll(rem);
    rem &= rem - 1;
    uint32_t pos = base + excl + k;
    k++;
    if (pos < ECAP2) elist[(size_t)bi * ECAP2 + pos] = ((uint32_t)i << 16) | (uint32_t)(j0 + jj);
  }
}

// ---------------- 6. greedy keep: word-ordered pass, early exit (R16/R22 verbatim) --
__global__ void __launch_bounds__(256) k_seq(const unsigned long long* __restrict__ diag,
                                             const uint32_t* __restrict__ ecnt,
                                             const uint32_t* __restrict__ elist,
                                             const int* __restrict__ scal,
                                             const float4* __restrict__ selbox,
                                             float* __restrict__ out) {
  __shared__ uint32_t pend32[2 * KW];
  __shared__ uint32_t keep32[2 * KW];
  __shared__ uint32_t wcnt_s[KW], wrank[KW], carry_s;
  const int t = threadIdx.x, lane = t & 63;

  if (t < 2 * KW) pend32[t] = 0;
  __syncthreads();

  if (t < 64) {
    uint32_t ec0 = ecnt[lane];
    ec0 = (ec0 > ECAP2) ? ECAP2 : ec0;
    uint32_t ec1 = 0;
    if (64 + lane < KW) {
      ec1 = ecnt[64 + lane];
      ec1 = (ec1 > ECAP2) ? ECAP2 : ec1;
    }
    int V = scal[4];
    if (V > (int)TOPK) V = (int)TOPK;

    unsigned long long mb = diag[lane];
    uint32_t cw = __builtin_amdgcn_readlane(ec0, 0);
    uint32_t en0 = elist[lane];
    uint32_t en1 = elist[64 + lane];

    uint32_t cum = 0;
    int cut = KW - 1;
    for (int c = 0; c < KW; c++) {
      unsigned long long mbn = 0;
      uint32_t cwn = 0, en0n = 0, en1n = 0;
      if (c + 1 < KW) {
        mbn = diag[(c + 1) * 64 + lane];
        cwn = (c + 1 < 64) ? __builtin_amdgcn_readlane(ec0, c + 1)
                           : __builtin_amdgcn_readlane(ec1, c + 1 - 64);
        en0n = elist[(size_t)(c + 1) * ECAP2 + lane];
        en1n = elist[(size_t)(c + 1) * ECAP2 + 64 + lane];
      }
      uint32_t plo = pend32[2 * c], phi = pend32[2 * c + 1];
      int d = V - c * 64;
      unsigned long long vinit =
          (d <= 0) ? 0ull : ((d >= 64) ? ~0ull : ((1ull << d) - 1));
      unsigned long long w = vinit & ~(((unsigned long long)phi << 32) | plo);
      unsigned long long sup = __ballot(mb != 0);
      unsigned long long rem = w & sup;
      while (rem) {
        int b = (int)__builtin_ctzll(rem);
        uint32_t mlo = __builtin_amdgcn_readlane((uint32_t)mb, b);
        uint32_t mhi = __builtin_amdgcn_readlane((uint32_t)(mb >> 32), b);
        w &= ~(((unsigned long long)mhi << 32) | mlo);
        rem = (b >= 63) ? 0ull : (w & sup & (~0ull << (b + 1)));
      }
      if (lane == 0) {
        keep32[2 * c] = (uint32_t)w;
        keep32[2 * c + 1] = (uint32_t)(w >> 32);
      }
      cum += (uint32_t)__popcll(w);
      if (cum >= OUTK) { cut = c; break; }
      if ((uint32_t)lane < cw) {
        uint32_t i = en0 >> 16, j = en0 & 0xFFFFu;
        if ((w >> (i & 63)) & 1ull) atomicOr(&pend32[j >> 5], 1u << (j & 31));
      }
      if ((uint32_t)(64 + lane) < cw) {
        uint32_t i = en1 >> 16, j = en1 & 0xFFFFu;
        if ((w >> (i & 63)) & 1ull) atomicOr(&pend32[j >> 5], 1u << (j & 31));
      }
      for (uint32_t k = 128 + (uint32_t)lane; k < cw; k += 64) {
        uint32_t e = elist[(size_t)c * ECAP2 + k];
        uint32_t i = e >> 16, j = e & 0xFFFFu;
        if ((w >> (i & 63)) & 1ull) atomicOr(&pend32[j >> 5], 1u << (j & 31));
      }
      mb = mbn; cw = cwn; en0 = en0n; en1 = en1n;
    }
    for (int wz = cut + 1 + lane; wz < KW; wz += 64) {
      keep32[2 * wz] = 0;
      keep32[2 * wz + 1] = 0;
    }
  }
  __syncthreads();

  if (t < KW)
    wcnt_s[t] = (uint32_t)(__popc(keep32[2 * t]) + __popc(keep32[2 * t + 1]));
  __syncthreads();
  if (t < 64) {
    uint32_t v = wcnt_s[t], p2 = v;
#pragma unroll
    for (int off = 1; off < 64; off <<= 1) {
      uint32_t x = __shfl_up(p2, off);
      if (lane >= off) p2 += x;
    }
    wrank[t] = p2 - v;
    if (t == 63) carry_s = p2;
  }
  __syncthreads();
  if (t >= 64 && t < KW) {
    uint32_t v = wcnt_s[t], p2 = v;
#pragma unroll
    for (int off = 1; off < 64; off <<= 1) {
      uint32_t x = __shfl_up(p2, off);
      if (lane >= off) p2 += x;
    }
    wrank[t] = carry_s + p2 - v;
  }
  __syncthreads();
  for (int o = t; o < OUTK * 4; o += 256) out[o] = 0.0f;
  __syncthreads();
  for (int r = t; r < (int)TOPK; r += 256) {
    unsigned long long w =
        ((unsigned long long)keep32[2 * (r >> 6) + 1] << 32) | keep32[2 * (r >> 6)];
    int b = r & 63;
    if ((w >> b) & 1ull) {
      uint32_t rank = wrank[r >> 6] + (uint32_t)__popcll(w & ((1ull << b) - 1ull));
      if (rank < OUTK) {
        float4 bx = selbox[r];
        out[rank * 4 + 0] = bx.x;
        out[rank * 4 + 1] = bx.y;
        out[rank * 4 + 2] = bx.z;
        out[rank * 4 + 3] = bx.w;
      }
    }
  }
}

// ---------------- launch ----------------
extern "C" void kernel_launch(void* const* d_in, const int* in_sizes, int n_in,
                              void* d_out, int out_size, void* d_ws, size_t ws_size,
                              hipStream_t stream) {
  const float* cls    = (const float*)d_in[0];
  const float* reg    = (const float*)d_in[1];
  const float* anchor = (const float*)d_in[2];
  float* out = (float*)d_out;
  char* ws = (char*)d_ws;

  float4*   roi     = (float4*)(ws + OFF_ROI);
  uint32_t* key     = (uint32_t*)(ws + OFF_KEY);
  uint32_t* hist16  = (uint32_t*)(ws + OFF_HIST16);
  uint32_t* hists   = (uint32_t*)(ws + OFF_HISTS);
  uint32_t* bsum    = (uint32_t*)(ws + OFF_BSUM);
  int*      scal    = (int*)(ws + OFF_SCAL);
  uint32_t* ecnt    = (uint32_t*)(ws + OFF_ECNT);
  unsigned long long* sortbuf = (unsigned long long*)(ws + OFF_SORT);
  float4*   selbox  = (float4*)(ws + OFF_SELBOX);
  unsigned long long* diag = (unsigned long long*)(ws + OFF_DIAG);
  uint32_t* elist   = (uint32_t*)(ws + OFF_ELIST);

  int blocks = (NN + 255) / 256;
  k_init<<<INIT_BLOCKS, 256, 0, stream>>>(ws);
  k_decode<<<blocks, 256, 0, stream>>>(cls, reg, anchor, roi, key, hist16);
  k_hsumS<<<NBLK, 256, 0, stream>>>(hist16, hists, bsum, scal);
  k_compact<<<blocks, 256, 0, stream>>>(key, scal, sortbuf);
  k_rank<<<SORTN / 32, 256, 0, stream>>>(sortbuf, scal, roi, selbox);
  k_mask<<<dim3(KW, KW), 64, 0, stream>>>(selbox, diag, ecnt, elist);
  k_seq<<<1, 256, 0, stream>>>(diag, ecnt, elist, scal, selbox, out);
}

// Round 26
// 82.850 us; speedup vs baseline: 1.6458x; 1.2010x over previous
//
#include <hip/hip_runtime.h>
#include <stdint.h>

#pragma clang fp contract(off)

#define NN    300000
#define TOPK  6000u
#define KW    94
#define KPAD  6016
#define SORTN 8192
#define NCHUNK 16
#define CSZ   512
#define OUTK  300
#define ECAP2 2048
#define NREP  8
#define NBLK  256
#define CUTW  16   // mask computes suppression rows bi < CUTW only (seq has exact fallback)

// ---------------- workspace layout (bytes) ----------------
static constexpr size_t OFF_ROI    = 0;                                   // NN*16
static constexpr size_t OFF_KEY    = OFF_ROI + (size_t)NN * 16;           // NN*4
static constexpr size_t OFF_HIST16 = ((OFF_KEY + (size_t)NN * 4 + 255) & ~(size_t)255); // NREP*65536*4
static constexpr size_t OFF_SCAL   = OFF_HIST16 + (size_t)NREP * 65536 * 4; // 256 B
static constexpr size_t OFF_ECNT   = OFF_SCAL + 256;                      // 94*4 pad 512
static constexpr size_t ZERO_BYTES = (OFF_ECNT + 512) - OFF_HIST16;
static constexpr size_t OFF_HISTS  = OFF_ECNT + 512;                      // 65536*4
static constexpr size_t OFF_BSUM   = OFF_HISTS + 65536 * 4;               // 256*4 pad 1024
static constexpr size_t OFF_SORT   = OFF_BSUM + 1024;                     // SORTN*8
static constexpr size_t OFF_SELBOX = OFF_SORT + (size_t)SORTN * 8;        // KPAD*16
static constexpr size_t OFF_DIAG   = ((OFF_SELBOX + (size_t)KPAD * 16 + 255) & ~(size_t)255); // KPAD*8
static constexpr size_t OFF_ELIST  = OFF_DIAG + (size_t)KPAD * 8;         // KW*ECAP2*4

// scal[]: [0]=P16 bin, [3]=compact counter, [4]=valid total, [8]=hsum done ctr

static constexpr uint32_t ZG = (uint32_t)(ZERO_BYTES / 16);
static constexpr uint32_t INIT_BLOCKS = (ZG + 255) / 256;

__device__ __forceinline__ uint32_t score_key(float s) {
  uint32_t u = __float_as_uint(s);
  u = (u >> 31) ? ~u : (u | 0x80000000u);
  return ~u;
}
__device__ __forceinline__ uint32_t hslot(uint32_t b) { return __brev(b) >> 16; }
__device__ __forceinline__ float rlf(float v, int l) {
  return __uint_as_float(__builtin_amdgcn_readlane(__float_as_uint(v), l));
}

// ---------------- 0. workspace init (hist replicas + scal + ecnt) ----------------
__global__ void __launch_bounds__(256) k_init(char* __restrict__ ws) {
  uint32_t idx = blockIdx.x * 256 + threadIdx.x;
  if (idx < ZG)
    ((uint4*)(ws + OFF_HIST16))[idx] = make_uint4(0u, 0u, 0u, 0u);
}

// ---------------- 1. decode + key + replicated 16-bit histogram ----------------
__global__ void k_decode(const float* __restrict__ cls, const float* __restrict__ reg,
                         const float* __restrict__ anchor, float4* __restrict__ roi,
                         uint32_t* __restrict__ key, uint32_t* __restrict__ hist16) {
  int i = blockIdx.x * blockDim.x + threadIdx.x;
  if (i >= NN) return;
  float c0 = cls[2 * i], c1 = cls[2 * i + 1];
  float m  = fmaxf(c0, c1);
  float a0 = c0 - m, a1 = c1 - m;
  float tn = fminf(a0, a1);
  float e  = (float)exp((double)tn);
  float e0 = (a0 == 0.0f) ? 1.0f : e;
  float e1 = (a1 == 0.0f) ? 1.0f : e;
  float s  = e1 / (e0 + e1);

  float4 a = ((const float4*)anchor)[i];
  float acx = (a.x + a.z) * 0.5f;
  float acy = (a.y + a.w) * 0.5f;
  float aw  = a.z - a.x;
  float ah  = a.w - a.y;
  float4 r = ((const float4*)reg)[i];
  float cx = r.x * aw + acx;
  float cy = r.y * ah + acy;
  float w  = (float)exp((double)r.z) * aw;
  float h  = (float)exp((double)r.w) * ah;
  float x1 = cx - w * 0.5f, y1 = cy - h * 0.5f;
  float x2 = cx + w * 0.5f, y2 = cy + h * 0.5f;
  x1 = fminf(fmaxf(x1, 0.0f), 1.0f);
  y1 = fminf(fmaxf(y1, 0.0f), 1.0f);
  x2 = fminf(fmaxf(x2, 0.0f), 1.0f);
  y2 = fminf(fmaxf(y2, 0.0f), 1.0f);
  float ws_ = x2 - x1, hs_ = y2 - y1;
  bool valid = (hs_ >= 0.001f) && (ws_ >= 0.001f);
  float msc = valid ? s : -__builtin_inff();
  uint32_t kk = score_key(msc);

  roi[i] = make_float4(x1, y1, x2, y2);
  key[i] = kk;
  if (valid) atomicAdd(&hist16[((blockIdx.x & (NREP - 1)) << 16) + hslot(kk >> 16)], 1u);
}

// ---------------- 2. hsum (256 blocks) + LAST BLOCK runs hierarchical scan --------
__global__ void __launch_bounds__(256) k_hsumS(const uint32_t* __restrict__ hist16,
                                               uint32_t* __restrict__ hists,
                                               uint32_t* __restrict__ bsum,
                                               int* __restrict__ scal) {
  __shared__ uint32_t red[256];
  __shared__ uint32_t cum[256];
  __shared__ int Bs;
  __shared__ int lastblk;
  int t = threadIdx.x;
  int b = blockIdx.x * 256 + t;
  uint32_t slot = hslot((uint32_t)b);
  uint32_t s = 0;
#pragma unroll
  for (int r = 0; r < NREP; r++) s += hist16[(r << 16) + slot];
  hists[b] = s;
  red[t] = s;
  __syncthreads();
  for (int off = 128; off > 0; off >>= 1) {
    if (t < off) red[t] += red[t + off];
    __syncthreads();
  }
  if (t == 0) bsum[blockIdx.x] = red[0];

  __syncthreads();
  if (t == 0) {
    __threadfence();
    uint32_t old = atomicAdd((uint32_t*)&scal[8], 1u);
    lastblk = (old == (uint32_t)(gridDim.x - 1));
  }
  __syncthreads();
  if (!lastblk) return;
  __threadfence();

  uint32_t v = bsum[t];
  cum[t] = v;
  if (t == 0) Bs = 256;
  __syncthreads();
  for (int off = 1; off < 256; off <<= 1) {
    uint32_t x = (t >= off) ? cum[t - off] : 0;
    __syncthreads();
    cum[t] += x;
    __syncthreads();
  }
  if (t == 255) scal[4] = (int)cum[255];
  if (cum[t] >= TOPK && (t == 0 || cum[t - 1] < TOPK)) Bs = t;
  __syncthreads();
  int B = Bs;
  if (B == 256) { if (t == 0) scal[0] = 65535; return; }
  uint32_t cumbase = (B > 0) ? cum[B - 1] : 0;
  __syncthreads();
  uint32_t h2 = hists[B * 256 + t];
  cum[t] = h2;
  __syncthreads();
  for (int off = 1; off < 256; off <<= 1) {
    uint32_t x = (t >= off) ? cum[t - off] : 0;
    __syncthreads();
    cum[t] += x;
    __syncthreads();
  }
  uint32_t cc = cumbase + cum[t];
  uint32_t cp = cc - h2;
  if (cc >= TOPK && cp < TOPK) scal[0] = B * 256 + t;
}

// ---------------- 3. compact candidates: prefix16 <= P16 ----------------
__global__ void k_compact(const uint32_t* __restrict__ key, int* __restrict__ scal,
                          unsigned long long* __restrict__ sortbuf) {
  __shared__ int lcnt, lbase;
  int t = threadIdx.x;
  int i = blockIdx.x * blockDim.x + t;
  if (t == 0) lcnt = 0;
  __syncthreads();
  bool sel = false;
  uint32_t kk = 0;
  int my = 0;
  if (i < NN) {
    uint32_t P = (uint32_t)scal[0];
    kk = key[i];
    if ((kk >> 16) <= P) { sel = true; my = atomicAdd(&lcnt, 1); }
  }
  __syncthreads();
  if (t == 0 && lcnt > 0) lbase = atomicAdd(&scal[3], lcnt);
  __syncthreads();
  if (sel) {
    int pos = lbase + my;
    if (pos < SORTN) sortbuf[pos] = (((unsigned long long)kk) << 32) | (uint32_t)i;
  }
}

// ---------------- 4a. per-chunk bitonic sort (pads >= total with ~0) ----------------
__global__ void __launch_bounds__(256) k_sortA(unsigned long long* __restrict__ sortbuf,
                                               const int* __restrict__ scal) {
  __shared__ unsigned long long sm[CSZ];
  int t = threadIdx.x;
  int total = scal[3];
  if (total > SORTN) total = SORTN;
  unsigned long long* chunk = sortbuf + (size_t)blockIdx.x * CSZ;
  int g0 = blockIdx.x * CSZ + t;
  sm[t] = (g0 < total) ? chunk[t] : ~0ull;
  sm[t + 256] = (g0 + 256 < total) ? chunk[t + 256] : ~0ull;
  __syncthreads();
  for (int k = 2; k <= CSZ; k <<= 1) {
    for (int j = k >> 1; j > 0; j >>= 1) {
      int i1 = ((t & ~(j - 1)) << 1) | (t & (j - 1));
      int i2 = i1 | j;
      bool up = ((i1 & k) == 0);
      unsigned long long a = sm[i1], b = sm[i2];
      if ((a > b) == up) { sm[i1] = b; sm[i2] = a; }
      __syncthreads();
    }
  }
  chunk[t] = sm[t];
  chunk[t + 256] = sm[t + 256];
}

// ---------------- 4b. multi-merge rank: one LANE per (element,chunk) pair (R22) -----
__global__ void __launch_bounds__(256) k_sortB(const unsigned long long* __restrict__ sortbuf,
                                               const float4* __restrict__ roi,
                                               float4* __restrict__ selbox) {
  int gt = blockIdx.x * 256 + threadIdx.x;
  int e  = gt >> 4;
  int c2 = gt & 15;
  int c  = e >> 9;
  unsigned long long val = sortbuf[e];
  const unsigned long long* base = sortbuf + ((size_t)c2 << 9);
  bool le = (c2 < c);
  uint32_t pos = 0;
#pragma unroll
  for (int s = CSZ; s > 0; s >>= 1) {
    if (pos + s <= CSZ) {
      unsigned long long v = base[pos + s - 1];
      if (le ? (v <= val) : (v < val)) pos += s;
    }
  }
  uint32_t rank = pos;
#pragma unroll
  for (int off = 8; off > 0; off >>= 1) rank += __shfl_xor(rank, off, 16);
  if (c2 == 0) {
    if (rank < TOPK) {
      uint32_t bi = (uint32_t)val;
      selbox[rank] = (bi < NN) ? roi[bi] : make_float4(0.f, 0.f, 0.f, 0.f);
    } else if (rank < KPAD) {
      selbox[rank] = make_float4(0.f, 0.f, 0.f, 0.f);
    }
  }
}

// ---------------- 5. suppression rows bi < CUTW only (LDS variant, R22) ----------
__global__ void __launch_bounds__(64) k_mask(const float4* __restrict__ selbox,
                                             unsigned long long* __restrict__ diag,
                                             uint32_t* __restrict__ ecnt,
                                             uint32_t* __restrict__ elist) {
  int bi = blockIdx.x, bj = blockIdx.y;   // bi < CUTW
  if (bj < bi) return;
  int t = threadIdx.x;
  __shared__ float4 jb[64];
  __shared__ float  ja[64];
  int j0 = bj * 64;
  float4 cb = selbox[j0 + t];
  jb[t] = cb;
  ja[t] = (cb.z - cb.x) * (cb.w - cb.y);
  __syncthreads();
  int i = bi * 64 + t;
  unsigned long long word = 0;
  if (i < (int)TOPK) {
    float4 bi4 = selbox[i];
    float ai = (bi4.z - bi4.x) * (bi4.w - bi4.y);
    for (int jj = 0; jj < 64; jj++) {
      int j = j0 + jj;
      float4 bb = jb[jj];
      float ltx = fmaxf(bi4.x, bb.x), lty = fmaxf(bi4.y, bb.y);
      float rbx = fminf(bi4.z, bb.z), rby = fminf(bi4.w, bb.w);
      float wx = fmaxf(rbx - ltx, 0.0f), wy = fmaxf(rby - lty, 0.0f);
      float inter = wx * wy;
      float iou = inter / (ai + ja[jj] - inter + 1e-9f);
      if (iou > 0.7f && j > i && j < (int)TOPK) word |= (1ull << jj);
    }
  }
  if (bi == bj) {
    diag[i] = word;
    return;
  }
  uint32_t cnt = (uint32_t)__popcll(word);
  uint32_t pre = cnt;
#pragma unroll
  for (int off = 1; off < 64; off <<= 1) {
    uint32_t v = __shfl_up(pre, off);
    if (t >= off) pre += v;
  }
  uint32_t total = __shfl(pre, 63);
  if (total == 0) return;
  uint32_t excl = pre - cnt;
  uint32_t base;
  if (t == 0) base = atomicAdd(&ecnt[bi], total);
  base = __shfl(base, 0);
  unsigned long long rem = word;
  uint32_t k = 0;
  while (rem) {
    int jj = (int)__builtin_ctzll(rem);
    rem &= rem - 1;
    uint32_t pos = base + excl + k;
    k++;
    if (pos < ECAP2) elist[(size_t)bi * ECAP2 + pos] = ((uint32_t)i << 16) | (uint32_t)(j0 + jj);
  }
}

// ---------------- 6. greedy keep: early-exit word pass + EXACT on-demand fallback ---
// Words c < CUTW: R16/R22-validated path (diag + elist + pend32). If OUTK keeps
// are not reached by word CUTW (3x margin over observed cut~5; never triggers
// on this data), an exact fallback computes suppression on demand: candidates
// tested vs kept boxes of words >= CUTW (broadcast selbox reads; suppression
// from words < CUTW is already in pend32, since trimmed mask rows cover ALL
// columns), then the R18-validated broadcast-readlane in-word greedy walk.
__global__ void __launch_bounds__(256) k_seq(const unsigned long long* __restrict__ diag,
                                             const uint32_t* __restrict__ ecnt,
                                             const uint32_t* __restrict__ elist,
                                             const int* __restrict__ scal,
                                             const float4* __restrict__ selbox,
                                             float* __restrict__ out) {
  __shared__ uint32_t pend32[2 * KW];
  __shared__ uint32_t keep32[2 * KW];
  __shared__ uint32_t wcnt_s[KW], wrank[KW], carry_s;
  const int t = threadIdx.x, lane = t & 63;
  const int NW = (KW < CUTW) ? KW : CUTW;

  if (t < 2 * KW) pend32[t] = 0;
  __syncthreads();

  if (t < 64) {
    uint32_t ec0 = (lane < NW) ? ecnt[lane] : 0;
    ec0 = (ec0 > ECAP2) ? ECAP2 : ec0;
    int V = scal[4];
    if (V > (int)TOPK) V = (int)TOPK;

    unsigned long long mb = diag[lane];
    uint32_t cw = __builtin_amdgcn_readlane(ec0, 0);
    uint32_t en0 = elist[lane];
    uint32_t en1 = elist[64 + lane];

    uint32_t cum = 0;
    int cut = KW - 1;
    bool done = false;

    // ---- phase 1: words [0, NW) with precomputed suppression ----
    for (int c = 0; c < NW; c++) {
      unsigned long long mbn = 0;
      uint32_t cwn = 0, en0n = 0, en1n = 0;
      if (c + 1 < NW) {
        mbn = diag[(c + 1) * 64 + lane];
        cwn = __builtin_amdgcn_readlane(ec0, c + 1);
        en0n = elist[(size_t)(c + 1) * ECAP2 + lane];
        en1n = elist[(size_t)(c + 1) * ECAP2 + 64 + lane];
      }
      uint32_t plo = pend32[2 * c], phi = pend32[2 * c + 1];
      int d = V - c * 64;
      unsigned long long vinit =
          (d <= 0) ? 0ull : ((d >= 64) ? ~0ull : ((1ull << d) - 1));
      unsigned long long w = vinit & ~(((unsigned long long)phi << 32) | plo);
      unsigned long long sup = __ballot(mb != 0);
      unsigned long long rem = w & sup;
      while (rem) {
        int b = (int)__builtin_ctzll(rem);
        uint32_t mlo = __builtin_amdgcn_readlane((uint32_t)mb, b);
        uint32_t mhi = __builtin_amdgcn_readlane((uint32_t)(mb >> 32), b);
        w &= ~(((unsigned long long)mhi << 32) | mlo);
        rem = (b >= 63) ? 0ull : (w & sup & (~0ull << (b + 1)));
      }
      if (lane == 0) {
        keep32[2 * c] = (uint32_t)w;
        keep32[2 * c + 1] = (uint32_t)(w >> 32);
      }
      cum += (uint32_t)__popcll(w);
      if (cum >= OUTK) { cut = c; done = true; break; }
      if ((uint32_t)lane < cw) {
        uint32_t i = en0 >> 16, j = en0 & 0xFFFFu;
        if ((w >> (i & 63)) & 1ull) atomicOr(&pend32[j >> 5], 1u << (j & 31));
      }
      if ((uint32_t)(64 + lane) < cw) {
        uint32_t i = en1 >> 16, j = en1 & 0xFFFFu;
        if ((w >> (i & 63)) & 1ull) atomicOr(&pend32[j >> 5], 1u << (j & 31));
      }
      for (uint32_t k = 128 + (uint32_t)lane; k < cw; k += 64) {
        uint32_t e = elist[(size_t)c * ECAP2 + k];
        uint32_t i = e >> 16, j = e & 0xFFFFu;
        if ((w >> (i & 63)) & 1ull) atomicOr(&pend32[j >> 5], 1u << (j & 31));
      }
      mb = mbn; cw = cwn; en0 = en0n; en1 = en1n;
    }

    // ---- phase 2: exact on-demand fallback for words [NW, KW) ----
    if (!done) {
      for (int c = NW; c < KW; c++) {
        int d = V - c * 64;
        if (d <= 0) {
          if (lane == 0) { keep32[2 * c] = 0; keep32[2 * c + 1] = 0; }
          continue;
        }
        unsigned long long vinit = (d >= 64) ? ~0ull : ((1ull << d) - 1);
        uint32_t plo = pend32[2 * c], phi = pend32[2 * c + 1];
        unsigned long long pend = vinit & ~(((unsigned long long)phi << 32) | plo);
        int j = c * 64 + lane;
        float4 bx = selbox[j];
        float aj = (bx.z - bx.x) * (bx.w - bx.y);
        // test vs kept boxes in words [NW, c) (broadcast uniform reads)
        bool sup = false;
        for (int wz = NW; wz < c; wz++) {
          unsigned long long kw =
              ((unsigned long long)keep32[2 * wz + 1] << 32) | keep32[2 * wz];
          while (kw) {
            int b = (int)__builtin_ctzll(kw);
            kw &= kw - 1;
            float4 kb = selbox[wz * 64 + b];
            float ak = (kb.z - kb.x) * (kb.w - kb.y);
            float ltx = fmaxf(kb.x, bx.x), lty = fmaxf(kb.y, bx.y);
            float rbx = fminf(kb.z, bx.z), rby = fminf(kb.w, bx.w);
            float wx = fmaxf(rbx - ltx, 0.0f), wy = fmaxf(rby - lty, 0.0f);
            float inter = wx * wy;
            float iou = inter / (ak + aj - inter + 1e-9f);
            sup |= (iou > 0.7f);
          }
        }
        pend &= ~__ballot(sup);
        // in-word greedy walk via broadcast readlane (R18-validated)
        unsigned long long kmask = 0;
        while (pend) {
          int b = (int)__builtin_ctzll(pend);
          kmask |= 1ull << b;
          float bxx = rlf(bx.x, b), byy = rlf(bx.y, b);
          float bzz = rlf(bx.z, b), bww = rlf(bx.w, b);
          float ab  = rlf(aj, b);
          float ltx = fmaxf(bxx, bx.x), lty = fmaxf(byy, bx.y);
          float rbx = fminf(bzz, bx.z), rby = fminf(bww, bx.w);
          float wx = fmaxf(rbx - ltx, 0.0f), wy = fmaxf(rby - lty, 0.0f);
          float inter = wx * wy;
          float iou = inter / (ab + aj - inter + 1e-9f);
          unsigned long long suppress = __ballot(iou > 0.7f);
          pend &= ~(1ull << b);
          pend &= ~(suppress & (~0ull << (b + 1)));
        }
        if (lane == 0) {
          keep32[2 * c] = (uint32_t)kmask;
          keep32[2 * c + 1] = (uint32_t)(kmask >> 32);
        }
        cum += (uint32_t)__popcll(kmask);
        if (cum >= OUTK) { cut = c; break; }
      }
    }
    // zero keep words beyond the cutoff
    for (int wz = cut + 1 + lane; wz < KW; wz += 64) {
      keep32[2 * wz] = 0;
      keep32[2 * wz + 1] = 0;
    }
  }
  __syncthreads();

  if (t < KW)
    wcnt_s[t] = (uint32_t)(__popc(keep32[2 * t]) + __popc(keep32[2 * t + 1]));
  __syncthreads();
  if (t < 64) {
    uint32_t v = wcnt_s[t], p2 = v;
#pragma unroll
    for (int off = 1; off < 64; off <<= 1) {
      uint32_t x = __shfl_up(p2, off);
      if (lane >= off) p2 += x;
    }
    wrank[t] = p2 - v;
    if (t == 63) carry_s = p2;
  }
  __syncthreads();
  if (t >= 64 && t < KW) {
    uint32_t v = wcnt_s[t], p2 = v;
#pragma unroll
    for (int off = 1; off < 64; off <<= 1) {
      uint32_t x = __shfl_up(p2, off);
      if (lane >= off) p2 += x;
    }
    wrank[t] = carry_s + p2 - v;
  }
  __syncthreads();
  for (int o = t; o < OUTK * 4; o += 256) out[o] = 0.0f;
  __syncthreads();
  for (int r = t; r < (int)TOPK; r += 256) {
    unsigned long long w =
        ((unsigned long long)keep32[2 * (r >> 6) + 1] << 32) | keep32[2 * (r >> 6)];
    int b = r & 63;
    if ((w >> b) & 1ull) {
      uint32_t rank = wrank[r >> 6] + (uint32_t)__popcll(w & ((1ull << b) - 1ull));
      if (rank < OUTK) {
        float4 bx = selbox[r];
        out[rank * 4 + 0] = bx.x;
        out[rank * 4 + 1] = bx.y;
        out[rank * 4 + 2] = bx.z;
        out[rank * 4 + 3] = bx.w;
      }
    }
  }
}

// ---------------- launch ----------------
extern "C" void kernel_launch(void* const* d_in, const int* in_sizes, int n_in,
                              void* d_out, int out_size, void* d_ws, size_t ws_size,
                              hipStream_t stream) {
  const float* cls    = (const float*)d_in[0];
  const float* reg    = (const float*)d_in[1];
  const float* anchor = (const float*)d_in[2];
  float* out = (float*)d_out;
  char* ws = (char*)d_ws;

  float4*   roi     = (float4*)(ws + OFF_ROI);
  uint32_t* key     = (uint32_t*)(ws + OFF_KEY);
  uint32_t* hist16  = (uint32_t*)(ws + OFF_HIST16);
  uint32_t* hists   = (uint32_t*)(ws + OFF_HISTS);
  uint32_t* bsum    = (uint32_t*)(ws + OFF_BSUM);
  int*      scal    = (int*)(ws + OFF_SCAL);
  uint32_t* ecnt    = (uint32_t*)(ws + OFF_ECNT);
  unsigned long long* sortbuf = (unsigned long long*)(ws + OFF_SORT);
  float4*   selbox  = (float4*)(ws + OFF_SELBOX);
  unsigned long long* diag = (unsigned long long*)(ws + OFF_DIAG);
  uint32_t* elist   = (uint32_t*)(ws + OFF_ELIST);

  int blocks = (NN + 255) / 256;
  k_init<<<INIT_BLOCKS, 256, 0, stream>>>(ws);
  k_decode<<<blocks, 256, 0, stream>>>(cls, reg, anchor, roi, key, hist16);
  k_hsumS<<<NBLK, 256, 0, stream>>>(hist16, hists, bsum, scal);
  k_compact<<<blocks, 256, 0, stream>>>(key, scal, sortbuf);
  k_sortA<<<NCHUNK, 256, 0, stream>>>(sortbuf, scal);
  k_sortB<<<SORTN * 16 / 256, 256, 0, stream>>>(sortbuf, roi, selbox);
  k_mask<<<dim3(CUTW, KW), 64, 0, stream>>>(selbox, diag, ecnt, elist);
  k_seq<<<1, 256, 0, stream>>>(diag, ecnt, elist, scal, selbox, out);
}